// Round 4
// baseline (458.108 us; speedup 1.0000x reference)
//
#include <hip/hip_runtime.h>
#include <stdint.h>
#include <stddef.h>

// Problem constants
constexpr int B_ = 16, N_ = 8, C_ = 3, H_ = 48, W_ = 48, K_ = 5, NK_ = 4;
constexpr int HW_ = H_ * W_;            // 2304
constexpr int IMGS_ = B_ * N_;          // 128
constexpr int TP_ = 52;                 // padded tile dim (48 + 2*2 halo)

typedef float f32x4 __attribute__((ext_vector_type(4)));

// Main kernel: ONE BLOCK PER (img, g). 576 threads = 9 waves; thread t owns
// pixel-quad px0 = t*4 (block covers all 2304 px). The block sweeps its g's
// 75 core planes IN LAYOUT ORDER: per iteration the 9 waves read exactly one
// contiguous 9216B plane, so the block's global stream is one sequential
// 691 KB read (vs. the previous 1KB-of-every-9KB scatter -> DRAM row thrash).
// Output: per-g partial (already multiplied by kw) to workspace.
__global__ __launch_bounds__(576) void kmain(const float* __restrict__ frames,
                                             const float* __restrict__ core,
                                             const float* __restrict__ kw,
                                             float* __restrict__ part) {
    __shared__ float tile[TP_][TP_];     // 10816 B: padded channel-sum of img

    int t = threadIdx.x;
    int bx = blockIdx.x;
    int img = bx >> 2;
    int g = bx & 3;

    // Phase 0: full-image padded channel-sum tile (zero border).
    // 2704 entries / 576 threads = 5 rounds; frames slab is L2/L3-resident
    // (4 g-blocks per img share it through L3).
    const float* fb = frames + (size_t)img * (C_ * HW_);
    for (int i = t; i < TP_ * TP_; i += 576) {
        int pr = i / TP_;
        int pc = i - pr * TP_;
        int hh = pr - 2, ww = pc - 2;
        float s = 0.f;
        if ((unsigned)hh < (unsigned)H_ && (unsigned)ww < (unsigned)W_) {
            const float* f = fb + hh * W_ + ww;
            s = f[0] + f[HW_] + f[2 * HW_];
        }
        tile[pr][pc] = s;
    }
    __syncthreads();

    int px0 = t * 4;
    int h0 = px0 / W_;
    int w0 = px0 - h0 * W_;      // %4 == 0 -> 16B-aligned LDS reads

    // 5x8 channel-sum window in registers (rows h0..h0+4, cols w0..w0+7,
    // padded coords). Row stride 208B, w0%4==0 -> aligned b128 pairs.
    float fs[5][8];
#pragma unroll
    for (int rr = 0; rr < 5; ++rr) {
        f32x4 a = *(const f32x4*)&tile[h0 + rr][w0];
        f32x4 b = *(const f32x4*)&tile[h0 + rr][w0 + 4];
        fs[rr][0] = a.x; fs[rr][1] = a.y; fs[rr][2] = a.z; fs[rr][3] = a.w;
        fs[rr][4] = b.x; fs[rr][5] = b.y; fs[rr][6] = b.z; fs[rr][7] = b.w;
    }

    // Phase 1: sequential sweep over the 75 planes (p = k*3 + c).
    const float* cp = core + ((size_t)img * 300 + (size_t)g * 75) * HW_ + px0;
    float acc[3][4] = {{0.f, 0.f, 0.f, 0.f}, {0.f, 0.f, 0.f, 0.f}, {0.f, 0.f, 0.f, 0.f}};
#pragma unroll
    for (int p = 0; p < 75; ++p) {
        f32x4 d = __builtin_nontemporal_load((const f32x4*)(cp + (size_t)p * HW_));
        int k = p / 3;              // all compile-time after unroll
        int c = p - k * 3;
        int di = k / 5, dj = k - di * 5;
        acc[c][0] += d.x * fs[di][dj + 0];
        acc[c][1] += d.y * fs[di][dj + 1];
        acc[c][2] += d.z * fs[di][dj + 2];
        acc[c][3] += d.w * fs[di][dj + 3];
    }

    // Epilogue: multiply by kw[img][g*3+c] and store per-g partial.
    const float* kp = kw + (size_t)img * (12 * HW_) + (size_t)(g * 3) * HW_ + px0;
    float* pp = part + ((size_t)(img * 4 + g) * 3) * HW_ + px0;
#pragma unroll
    for (int c = 0; c < 3; ++c) {
        f32x4 kd = __builtin_nontemporal_load((const f32x4*)(kp + (size_t)c * HW_));
        f32x4 o;
        o.x = acc[c][0] * kd.x;
        o.y = acc[c][1] * kd.y;
        o.z = acc[c][2] * kd.z;
        o.w = acc[c][3] * kd.w;
        *(f32x4*)(pp + (size_t)c * HW_) = o;
    }
}

// Reduce the 4 g-partials: outi = 0.25 * sum_g part[img][g][c][px]
__global__ void kred(const float* __restrict__ part, float* __restrict__ outi) {
    int id = blockIdx.x * blockDim.x + threadIdx.x;   // quad id
    if (id >= IMGS_ * 3 * HW_ / 4) return;
    int img = id / (3 * HW_ / 4);
    int rem = id - img * (3 * HW_ / 4);
    size_t off = (size_t)rem * 4;                     // combined c*HW + px
    const float* p0 = part + (size_t)img * (12 * HW_) + off;
    f32x4 a = *(const f32x4*)(p0);
    f32x4 b = *(const f32x4*)(p0 + 3 * HW_);
    f32x4 c = *(const f32x4*)(p0 + 6 * HW_);
    f32x4 d = *(const f32x4*)(p0 + 9 * HW_);
    f32x4 o = (a + b + c + d) * 0.25f;
    *(f32x4*)(outi + (size_t)img * (3 * HW_) + off) = o;
}

// pred_img[b,c,h,w] = mean over n of pred_img_i
__global__ void kmean(const float* __restrict__ outi, float* __restrict__ outm) {
    int id = blockIdx.x * blockDim.x + threadIdx.x;
    if (id >= B_ * 3 * HW_) return;
    int b = id / (3 * HW_);
    int rem = id - b * (3 * HW_);
    const float* p = outi + (size_t)b * (N_ * 3 * HW_) + rem;
    float s = 0.f;
#pragma unroll
    for (int n = 0; n < N_; ++n) s += p[(size_t)n * 3 * HW_];
    outm[id] = s * 0.125f;
}

extern "C" void kernel_launch(void* const* d_in, const int* in_sizes, int n_in,
                              void* d_out, int out_size, void* d_ws, size_t ws_size,
                              hipStream_t stream) {
    const float* frames = (const float*)d_in[0];   // [B,N,3,H,W]
    const float* core = (const float*)d_in[1];     // [B,N,300,H,W] (flat middle dims)
    const float* kw = (const float*)d_in[2];       // [B,N,4,3,H,W]
    float* part = (float*)d_ws;                    // [IMGS][4][3][HW] = 14.16 MB
    float* outi = (float*)d_out;                   // pred_img_i: [B,N,3,H,W]
    float* outm = outi + (size_t)B_ * N_ * 3 * HW_; // pred_img: [B,3,H,W]

    kmain<<<IMGS_ * NK_, 576, 0, stream>>>(frames, core, kw, part);
    kred<<<(IMGS_ * 3 * HW_ / 4 + 255) / 256, 256, 0, stream>>>(part, outi);
    kmean<<<(B_ * 3 * HW_ + 255) / 256, 256, 0, stream>>>(outi, outm);
}

// Round 5
// 445.575 us; speedup vs baseline: 1.0281x; 1.0281x over previous
//
#include <hip/hip_runtime.h>
#include <stdint.h>
#include <stddef.h>

// Problem constants
constexpr int B_ = 16, N_ = 8, C_ = 3, H_ = 48, W_ = 48, K_ = 5, NK_ = 4;
constexpr int HW_ = H_ * W_;            // 2304
constexpr int IMGS_ = B_ * N_;          // 128
constexpr int PW_ = W_ + 4;             // 52 (padded width)
constexpr int PH_ = H_ + 4;             // 52
constexpr int PHW_ = PH_ * PW_;         // 2704
constexpr int CHUNKS_ = HW_ / 256;      // 9 chunks of 64 quads per image

typedef float f32x4 __attribute__((ext_vector_type(4)));

// BEST MEASURED VERSION (round 2: 447.3 us). Round-4's sequential-sweep
// restructure regressed (458.1) -> DRAM scatter is not a loss; round-3's
// kcs fusion was flat (447.98) -> prologue latency is sub-noise. This
// c-split structure is at the kernel-side memory floor:
//   - core (354 MB) is read exactly once, coalesced 1KB/wave bursts;
//   - grid = 3456 blocks (~13/CU queued) gives ample MLP;
//   - remaining window time is harness poison-fill + input-restore traffic.

// Kernel 1: padded channel-sum of frames: cs[img][52][52] (fp32), zero border.
__global__ void kcs(const float* __restrict__ frames, float* __restrict__ cs) {
    int id = blockIdx.x * blockDim.x + threadIdx.x;
    if (id >= IMGS_ * PHW_) return;
    int img = id / PHW_;
    int rem = id - img * PHW_;
    int ph = rem / PW_;
    int pw = rem - ph * PW_;
    int h = ph - 2, w = pw - 2;
    float s = 0.f;
    if ((unsigned)h < (unsigned)H_ && (unsigned)w < (unsigned)W_) {
        const float* f = frames + (size_t)img * (C_ * HW_) + h * W_ + w;
        s = f[0] + f[HW_] + f[2 * HW_];
    }
    cs[id] = s;
}

// Kernel 2: main fused conv, ONE CHANNEL PER BLOCK (grid = imgs*chunks*3).
// Block = 256 threads = 4 waves; wave g computes the partial
// kw[g,c] * sum_k core[g*75+k*3+c] * fs for 64 pixel-quads of channel c,
// then a 4-way LDS reduce over g.
__global__ __launch_bounds__(256) void kmain(const float* __restrict__ core,
                                             const float* __restrict__ kw,
                                             const float* __restrict__ cs,
                                             float* __restrict__ out) {
    __shared__ float red[4][4][64];      // [g][j][q] = 4 KB

    int t = threadIdx.x;
    int q = t & 63;        // quad index within chunk
    int g = t >> 6;        // kernel-weight group = wave id
    int bx = blockIdx.x;
    int c = bx % 3;        // channel fastest: consecutive blocks stream
    int ic = bx / 3;       //   adjacent core planes (k*3+c interleave)
    int img = ic / CHUNKS_;
    int chunk = ic - img * CHUNKS_;
    int pix0 = chunk * 256 + q * 4;
    int h = pix0 / W_;
    int w0 = pix0 - h * W_;

    // 5x8 channel-sum tile (padded coords: rows h..h+4, cols w0..w0+7).
    // cs is 1.4 MB total -> the 3 channel-blocks per chunk re-read it from L2/L3.
    float fs[5][8];
    const float* csp = cs + img * PHW_ + h * PW_ + w0;
#pragma unroll
    for (int rr = 0; rr < 5; ++rr) {
        f32x4 a = *(const f32x4*)(csp + rr * PW_);
        f32x4 b = *(const f32x4*)(csp + rr * PW_ + 4);
        fs[rr][0] = a.x; fs[rr][1] = a.y; fs[rr][2] = a.z; fs[rr][3] = a.w;
        fs[rr][4] = b.x; fs[rr][5] = b.y; fs[rr][6] = b.z; fs[rr][7] = b.w;
    }

    // core plane (g*75 + k*3 + c), stream-once -> nontemporal (don't thrash L2).
    const float* cp = core + (size_t)img * (300 * HW_)
                           + (size_t)(g * 75 + c) * HW_ + pix0;

    float t0 = 0.f, t1 = 0.f, t2 = 0.f, t3 = 0.f;
#pragma unroll
    for (int k = 0; k < 25; ++k) {
        f32x4 d = __builtin_nontemporal_load((const f32x4*)(cp + (size_t)(k * 3) * HW_));
        int di = k / 5, dj = k - di * 5;
        t0 += d.x * fs[di][dj + 0];
        t1 += d.y * fs[di][dj + 1];
        t2 += d.z * fs[di][dj + 2];
        t3 += d.w * fs[di][dj + 3];
    }
    f32x4 kd = __builtin_nontemporal_load(
        (const f32x4*)(kw + (size_t)img * (12 * HW_) + (size_t)(g * 3 + c) * HW_ + pix0));
    red[g][0][q] = kd.x * t0;
    red[g][1][q] = kd.y * t1;
    red[g][2][q] = kd.z * t2;
    red[g][3][q] = kd.w * t3;

    __syncthreads();

    // 4-way reduce over g; threads 0..63, thread q' handles 4 pixels.
    if (t < 64) {
        f32x4 o;
#pragma unroll
        for (int j = 0; j < 4; ++j) {
            o[j] = 0.25f * (red[0][j][t] + red[1][j][t] + red[2][j][t] + red[3][j][t]);
        }
        *(f32x4*)(out + (size_t)img * (3 * HW_) + (size_t)c * HW_ + chunk * 256 + t * 4) = o;
    }
}

// Kernel 3: pred_img[b,c,h,w] = mean over n of pred_img_i
__global__ void kmean(const float* __restrict__ outi, float* __restrict__ outm) {
    int id = blockIdx.x * blockDim.x + threadIdx.x;
    if (id >= B_ * 3 * HW_) return;
    int b = id / (3 * HW_);
    int rem = id - b * (3 * HW_);
    const float* p = outi + (size_t)b * (N_ * 3 * HW_) + rem;
    float s = 0.f;
#pragma unroll
    for (int n = 0; n < N_; ++n) s += p[(size_t)n * 3 * HW_];
    outm[id] = s * 0.125f;
}

extern "C" void kernel_launch(void* const* d_in, const int* in_sizes, int n_in,
                              void* d_out, int out_size, void* d_ws, size_t ws_size,
                              hipStream_t stream) {
    const float* frames = (const float*)d_in[0];   // [B,N,3,H,W]
    const float* core = (const float*)d_in[1];     // [B,N,300,H,W] (flat middle dims)
    const float* kw = (const float*)d_in[2];       // [B,N,4,3,H,W]
    float* cs = (float*)d_ws;                      // 128*52*52 fp32 = 1.38 MB
    float* outi = (float*)d_out;                   // pred_img_i: [B,N,3,H,W]
    float* outm = outi + (size_t)B_ * N_ * 3 * HW_; // pred_img: [B,3,H,W]

    kcs<<<(IMGS_ * PHW_ + 255) / 256, 256, 0, stream>>>(frames, cs);
    kmain<<<IMGS_ * CHUNKS_ * 3, 256, 0, stream>>>(core, kw, cs, outi);
    kmean<<<(B_ * 3 * HW_ + 255) / 256, 256, 0, stream>>>(outi, outm);
}